// Round 1
// 1807.680 us; speedup vs baseline: 1.1049x; 1.1049x over previous
//
#include <hip/hip_runtime.h>
#include <math.h>

// ---------------- constants ----------------
#define DTMEM 0.1f   // DT*TAU_MEM_INV
#define DTSYN 0.2f   // DT*TAU_SYN_INV
#define DTTR  0.02f  // DT*TAU_PRE_INV == DT*TAU_POST_INV

static constexpr int B = 32, T = 32;
static constexpr int HD = 60, H1 = 56, HP = 28, H2 = 24;
static constexpr int LD  = HD*HD;   // 3600
static constexpr int L1N = H1*H1;   // 3136
static constexpr int LP  = HP*HP;   // 784
static constexpr int L2N = H2*H2;   // 576

// lif0 state: thread-slot-major [b][og:8][yh:2][i:7][tid:448] float2
static constexpr size_t SST  = (size_t)B*8*2*7*448*2;          // floats (=3,211,264)
// conv2 state: thread-slot-major [b][jg:13][slot:6][tid:192] float4
static constexpr size_t SST2 = (size_t)B*13*6*192*4;           // floats (=1,916,928)

// float offsets: zero region is [OV0, OZEND)
static constexpr size_t OW1   = 0;                             // 1500
static constexpr size_t OV0   = OW1 + 1500;
static constexpr size_t OI0   = OV0   + SST;
static constexpr size_t OTQ1  = OI0   + SST;
static constexpr size_t OTP1A = OTQ1  + SST;                   // [B,60,60]
static constexpr size_t OTP2  = OTP1A + (size_t)B*LD;          // [B,30,28,28]
static constexpr size_t OV1S  = OTP2  + (size_t)B*30*LP;
static constexpr size_t OI1S  = OV1S  + SST2;
static constexpr size_t OTQ2S = OI1S  + SST2;
static constexpr size_t OZEND = OTQ2S + SST2;                  // end of zero region
static constexpr size_t OTP1B = OZEND;                         // [B,60,60] pong
static constexpr size_t OZ3   = OTP1B + (size_t)B*LD;          // [B,30,28,28]
static constexpr size_t OZ4S  = OZ3   + (size_t)B*30*LP;      // (unused now, kept for layout)
static constexpr size_t OE2P  = OZ4S  + SST2;                  // (unused now)
static constexpr size_t OE2M  = OE2P  + 75000;                 // (unused now)
static constexpr size_t OP1   = OE2M  + 75000;                 // [30][50][64]
static constexpr size_t OG    = OP1   + 96000;                 // [T][3200]
static constexpr size_t OHH   = OG    + (size_t)T*3200;        // [T][500]
static constexpr size_t OW2P  = OHH   + (size_t)T*500;         // [100][30][28]
static constexpr size_t OCNZ  = OW2P  + 84000;                 // int[960][4]
static constexpr size_t OTOT  = OCNZ  + 3840;
// new buffers for MFMA correlation path:
static constexpr size_t OEPP  = OTOT;                          // E2P partials [32][75000] f32
static constexpr size_t OEMP  = OEPP + (size_t)B*75000;        // E2M partials [32][75000] f32
static constexpr size_t OPHI  = OEMP + (size_t)B*75000;        // tp2 hi plane [B][30][784] u16
static constexpr size_t OPLO  = OPHI + 376320;                 // tp2 lo plane
static constexpr size_t OPZ3  = OPLO + 376320;                 // z3 bf16 plane
static constexpr size_t OQZ4  = OPZ3 + 376320;                 // z4 bf16 [B][112][576] u16
static constexpr size_t OQHI  = OQZ4 + 1032192;                // tq2 hi plane
static constexpr size_t OQLO  = OQHI + 1032192;                // tq2 lo plane
static constexpr size_t OTOT2 = OQLO + 1032192;

struct DK { float v[25]; };

typedef __attribute__((ext_vector_type(8))) short bfx8;
typedef __attribute__((ext_vector_type(4))) float f32x4;

static __device__ __forceinline__ unsigned short f2bf(float f) {
    unsigned u = __float_as_uint(f);
    return (unsigned short)((u + 0x7FFFu + ((u >> 16) & 1u)) >> 16);
}
static __device__ __forceinline__ float bf2f(unsigned short h) {
    return __uint_as_float(((unsigned)h) << 16);
}

// ================= Launch A: z=0 front(t) y-half blocks; z=1 w2-apply(t-1) =========
// front: grid (8 og, 64 = b*2+yh, 2), block 448 = (oo:4, xq:4, y:28).
__global__ __launch_bounds__(448) void k_front(
        const float* __restrict__ x, const float* __restrict__ b1,
        const float* __restrict__ b2, const float* __restrict__ w1c,
        const float* __restrict__ tp1r, float* __restrict__ tp1w,
        float* __restrict__ v0, float* __restrict__ i0, float* __restrict__ tq1,
        float* __restrict__ z3, float* __restrict__ tp2,
        float* __restrict__ part, int* __restrict__ cnz4,
        float* __restrict__ w2p,
        unsigned short* __restrict__ uhi, unsigned short* __restrict__ ulo,
        unsigned short* __restrict__ uz3,
        const float* __restrict__ EPp, const float* __restrict__ EMp,
        DK dk, int t) {
    if (blockIdx.z == 1) {
        if (t == 0) return;
        int lb = blockIdx.y*8 + blockIdx.x;
        int e = lb*448 + threadIdx.x;
        if (e < 75000) {
            int j = e / 750, r = e % 750, c = r / 25, p = r % 25;
            size_t f = ((size_t)j*30 + c)*28 + p;
            float w = w2p[f];
            float ep = 0.f, em = 0.f;
            #pragma unroll 4
            for (int bb = 0; bb < 32; bb++) {
                ep += EPp[(size_t)bb*75000 + e];
                em += EMp[(size_t)bb*75000 + e];
            }
            float dwp = 0.004f * fmaxf(1.0f - w, 0.0f) * ep;
            float dwm = 0.003f * fmaxf(w, 0.0f) * em;
            w2p[f] = fminf(fmaxf(w + dwp - dwm, 0.0f), 1.0f);
        }
        return;
    }
    __shared__ __attribute__((aligned(16))) float xsh[36*64];   // x rows [y0, y0+36)
    __shared__ __attribute__((aligned(16))) float zsh[32*60];   // DoG rows [y0, y0+32)
    __shared__ __attribute__((aligned(16))) float tsh[32*60];   // tp1 rows [y0, y0+32)
    __shared__ float red[700];                                   // 7 waves x 100
    __shared__ float wd[100];
    __shared__ int sflags[8];
    int og = blockIdx.x, by = blockIdx.y, tid = threadIdx.x;
    int b = by >> 1, yh = by & 1, y0 = yh*28;
    {
        const float4* xs = (const float4*)(x + ((size_t)t*B + b)*4096) + y0*16;
        const float4* ts = (const float4*)(tp1r + (size_t)b*LD) + y0*15;
        for (int i = tid; i < 576; i += 448) ((float4*)xsh)[i] = xs[i];
        for (int i = tid; i < 480; i += 448) ((float4*)tsh)[i] = ts[i];
    }
    if (tid < 100) {
        int oo2 = tid / 25, p = tid % 25;
        int o2 = og*4 + oo2; if (o2 > 29) o2 = 29;
        wd[tid] = w1c[o2*50 + p] - w1c[o2*50 + 25 + p];
    }
    if (tid < 8) sflags[tid] = 0;
    __syncthreads();
    float bias = b1[0] - b2[0];
    // DoG + tp1 trace on local rows (og==0 persists tp1; overlap rows identical)
    for (int idx = tid; idx < 1920; idx += 448) {
        int lr = idx / 60, c = idx % 60;
        float a = 0.f;
        #pragma unroll
        for (int kh = 0; kh < 5; kh++)
            #pragma unroll
            for (int kw = 0; kw < 5; kw++)
                a = fmaf(dk.v[kh*5+kw], xsh[(lr+kh)*64 + c + kw], a);
        float zv = a + bias;
        zsh[idx] = zv;
        float tp = tsh[idx];
        tp = tp + DTTR*(zv - tp);
        tsh[idx] = tp;
        if (og == 0) tp1w[(size_t)b*LD + (y0 + lr)*60 + c] = tp;
    }
    __syncthreads();
    int oo = tid & 3, xq = (tid >> 2) & 3, y = tid >> 4;   // y local [0,28)
    int o = og*4 + oo, x0 = xq*14;
    bool valid = (o < 30);
    float zn[14], tn[14];
    float zs = 0.f, qs = 0.f;
    bool anym = false;
    if (valid) {
        float acc[14];
        #pragma unroll
        for (int k = 0; k < 14; k++) acc[k] = 0.f;
        #pragma unroll
        for (int kh = 0; kh < 5; kh++) {
            float rr[18];
            const float2* r2 = (const float2*)&zsh[(y+kh)*HD + x0];
            #pragma unroll
            for (int i = 0; i < 9; i++) ((float2*)rr)[i] = r2[i];
            #pragma unroll
            for (int kw = 0; kw < 5; kw++) {
                float w = wd[oo*25 + kh*5 + kw];
                #pragma unroll
                for (int k = 0; k < 14; k++) acc[k] = fmaf(w, rr[k+kw], acc[k]);
            }
        }
        // LIF0 + tq1 in slot-major float2 (coalesced)
        float2* v0p = (float2*)v0;
        float2* i0p = (float2*)i0;
        float2* tq1p = (float2*)tq1;
        size_t sb = ((size_t)((b*8 + og)*2 + yh)*7)*448 + tid;
        #pragma unroll
        for (int i = 0; i < 7; i++) {
            float2 v2 = v0p[sb + (size_t)i*448];
            float2 c2 = i0p[sb + (size_t)i*448];
            float2 t2 = tq1p[sb + (size_t)i*448];
            float2 vn, in, tn2;
            #pragma unroll
            for (int k = 0; k < 2; k++) {
                int e = i*2 + k;
                float vv = k ? v2.y : v2.x, cc = k ? c2.y : c2.x, tt = k ? t2.y : t2.x;
                float vd = vv + DTMEM*(cc - vv);
                float z = (vd > 15.0f) ? 1.0f : 0.0f;
                float vo = (1.0f - z)*vd;
                float io_ = (cc - DTSYN*cc) + acc[e];
                float tq = tt + DTTR*(z - tt);
                if (k) { vn.y = vo; in.y = io_; tn2.y = tq; } else { vn.x = vo; in.x = io_; tn2.x = tq; }
                zn[e] = z; tn[e] = tq;
            }
            v0p[sb + (size_t)i*448] = vn;
            i0p[sb + (size_t)i*448] = in;
            tq1p[sb + (size_t)i*448] = tn2;
        }
        #pragma unroll
        for (int k = 0; k < 14; k++) { zs += zn[k]; qs += tn[k]; }
        float mx[7];
        #pragma unroll
        for (int k = 0; k < 7; k++) mx[k] = fmaxf(zn[2*k], zn[2*k+1]);
        #pragma unroll
        for (int k = 0; k < 7; k++) {
            float pm = __shfl_xor(mx[k], 16, 64);   // y-partner (y^1)
            mx[k] = fmaxf(mx[k], pm);
        }
        if ((y & 1) == 0) {
            int py = yh*14 + (y >> 1);
            size_t pb = ((size_t)(b*30 + o)*HP + py)*HP + xq*7;
            #pragma unroll
            for (int k = 0; k < 7; k++) {
                float m = mx[k];
                anym = anym || (m != 0.f);
                z3[pb + k] = m;
                float tpv = tp2[pb + k];
                float tnew = tpv + DTTR*(m - tpv);
                tp2[pb + k] = tnew;
                // bf16 planes for MFMA correlation
                unsigned short h = f2bf(tnew);
                uhi[pb + k] = h;
                ulo[pb + k] = f2bf(tnew - bf2f(h));
                uz3[pb + k] = (m != 0.f) ? (unsigned short)0x3F80 : (unsigned short)0;
            }
        }
    }
    if (anym) atomicOr(&sflags[oo*2 + (xq >> 1)], 1);
    int lane = tid & 63, wave = tid >> 6;
    // pass 1: minus correlation (unfold(z0) x tq1_new)
    {
        float a[25];
        #pragma unroll
        for (int p = 0; p < 25; p++) a[p] = 0.f;
        if (valid && qs != 0.f) {
            #pragma unroll
            for (int kh = 0; kh < 5; kh++) {
                float rr[18];
                const float2* r2 = (const float2*)&zsh[(y+kh)*HD + x0];
                #pragma unroll
                for (int i = 0; i < 9; i++) ((float2*)rr)[i] = r2[i];
                #pragma unroll
                for (int kw = 0; kw < 5; kw++)
                    #pragma unroll
                    for (int k = 0; k < 14; k++)
                        a[kh*5+kw] = fmaf(rr[k+kw], tn[k], a[kh*5+kw]);
            }
        }
        #pragma unroll
        for (int q = 0; q < 25; q++) {
            float v = a[q];
            v += __shfl_xor(v, 4, 64);
            v += __shfl_xor(v, 8, 64);
            v += __shfl_xor(v, 16, 64);
            v += __shfl_xor(v, 32, 64);
            if (lane < 4) red[wave*100 + lane*25 + q] = v;
        }
    }
    __syncthreads();
    if (tid < 100) {
        int oo2 = tid / 25, q = tid % 25;
        float s = 0.f;
        #pragma unroll
        for (int w = 0; w < 7; w++) s += red[w*100 + oo2*25 + q];
        int o2 = og*4 + oo2;
        if (o2 < 30) part[((size_t)(o2*50 + 25 + q) << 6) + b*2 + yh] = s;
    }
    if (tid < 8) {
        int o2 = og*4 + (tid >> 1);
        if (o2 < 30) cnz4[(b*30 + o2)*4 + yh*2 + (tid & 1)] = sflags[tid];
    }
    __syncthreads();
    // pass 2: plus correlation (unfold(tp1_new) x z2)
    {
        float a[25];
        #pragma unroll
        for (int p = 0; p < 25; p++) a[p] = 0.f;
        if (valid && zs != 0.f) {
            #pragma unroll
            for (int kh = 0; kh < 5; kh++) {
                float rr[18];
                const float2* r2 = (const float2*)&tsh[(y+kh)*HD + x0];
                #pragma unroll
                for (int i = 0; i < 9; i++) ((float2*)rr)[i] = r2[i];
                #pragma unroll
                for (int kw = 0; kw < 5; kw++)
                    #pragma unroll
                    for (int k = 0; k < 14; k++)
                        a[kh*5+kw] = fmaf(rr[k+kw], zn[k], a[kh*5+kw]);
            }
        }
        #pragma unroll
        for (int q = 0; q < 25; q++) {
            float v = a[q];
            v += __shfl_xor(v, 4, 64);
            v += __shfl_xor(v, 8, 64);
            v += __shfl_xor(v, 16, 64);
            v += __shfl_xor(v, 32, 64);
            if (lane < 4) red[wave*100 + lane*25 + q] = v;
        }
    }
    __syncthreads();
    if (tid < 100) {
        int oo2 = tid / 25, q = tid % 25;
        float s = 0.f;
        #pragma unroll
        for (int w = 0; w < 7; w++) s += red[w*100 + oo2*25 + q];
        int o2 = og*4 + oo2;
        if (o2 < 30) part[((size_t)(o2*50 + q) << 6) + b*2 + yh] = s;
    }
}

// ================= Launch B: conv2 + LIF1 + tq2 + g (slot-major state) =========
// grid (13 jg, 32 b), block 192 = (jp:4, xh:2, y:24).
__global__ __launch_bounds__(192) void k_conv2lif(
        const float* __restrict__ w2p, const float* __restrict__ z3,
        const int* __restrict__ cnz4,
        float* __restrict__ v1s, float* __restrict__ i1s,
        float* __restrict__ tq2s,
        unsigned short* __restrict__ z4b, unsigned short* __restrict__ tqh,
        unsigned short* __restrict__ tql,
        float* __restrict__ g_t) {
    __shared__ __attribute__((aligned(16))) float spre[LP];
    __shared__ int sjany[8];
    int jg = blockIdx.x, b = blockIdx.y, tid = threadIdx.x;
    int jb0 = jg*8;
    if (tid < 8) sjany[tid] = 0;
    int jp = tid & 3;
    int j0 = jb0 + jp*2;
    int y = tid >> 3, x0 = ((tid >> 2) & 1)*12;
    int ja = (j0 < 100) ? j0 : 99;
    int jbb = (j0+1 < 100) ? j0+1 : 99;
    float acc0[12], acc1[12];
    #pragma unroll
    for (int xq = 0; xq < 12; xq++) { acc0[xq] = 0.f; acc1[xq] = 0.f; }
    #pragma unroll 1
    for (int c = 0; c < 30; c++) {
        const int* cz = cnz4 + (b*30 + c)*4;
        bool act = (cz[0] | cz[1] | cz[2] | cz[3]) != 0;
        __syncthreads();
        if (act) {
            const float4* src = (const float4*)(z3 + (size_t)(b*30 + c)*LP);
            float4* dst = (float4*)spre;
            for (int i = tid; i < 196; i += 192) dst[i] = src[i];
        }
        __syncthreads();
        if (!act) continue;
        float wa[28], wb[28];
        #pragma unroll
        for (int i = 0; i < 7; i++) {
            ((float4*)wa)[i] = ((const float4*)(w2p + ((size_t)ja*30 + c)*28))[i];
            ((float4*)wb)[i] = ((const float4*)(w2p + ((size_t)jbb*30 + c)*28))[i];
        }
        #pragma unroll
        for (int kh = 0; kh < 5; kh++) {
            float rr[16];
            const float4* r4 = (const float4*)&spre[(y+kh)*HP + x0];
            #pragma unroll
            for (int i = 0; i < 4; i++) ((float4*)rr)[i] = r4[i];
            #pragma unroll
            for (int kw = 0; kw < 5; kw++) {
                float w0 = wa[kh*5+kw], w1 = wb[kh*5+kw];
                #pragma unroll
                for (int xq = 0; xq < 12; xq++) {
                    acc0[xq] = fmaf(w0, rr[xq+kw], acc0[xq]);
                    acc1[xq] = fmaf(w1, rr[xq+kw], acc1[xq]);
                }
            }
        }
    }
    float4* v1p = (float4*)v1s; float4* i1p = (float4*)i1s;
    float4* t2p = (float4*)tq2s;
    size_t sb2 = ((size_t)(b*13 + jg)*6)*192 + tid;
    bool spk0 = false, spk1 = false;
    #pragma unroll
    for (int jj = 0; jj < 2; jj++) {
        bool anyspk = false;
        int j_eff = jj ? jbb : ja;
        #pragma unroll
        for (int i = 0; i < 3; i++) {
            size_t si = sb2 + (size_t)(jj*3 + i)*192;
            float4 v4 = v1p[si];
            float4 c4 = i1p[si];
            float4 t4 = t2p[si];
            float4 vn, in, zn, tn;
            float* vp=(float*)&v4; float* cp=(float*)&c4; float* tp=(float*)&t4;
            float* vnp=(float*)&vn; float* inp=(float*)&in; float* znp=(float*)&zn; float* tnp=(float*)&tn;
            #pragma unroll
            for (int k = 0; k < 4; k++) {
                float a = jj ? acc1[i*4+k] : acc0[i*4+k];
                float vd = vp[k] + DTMEM*(cp[k] - vp[k]);
                float z = (vd > 10.0f) ? 1.0f : 0.0f;
                vnp[k] = (1.0f - z)*vd;
                inp[k] = (cp[k] - DTSYN*cp[k]) + 10.0f*a;
                znp[k] = z;
                tnp[k] = tp[k] + DTTR*(z - tp[k]);
                anyspk = anyspk || (z != 0.f);
            }
            v1p[si] = vn;
            i1p[si] = in;
            t2p[si] = tn;
            // bf16 planes [b][j:112][l:576], l = y*24 + x0 + i*4 + k
            size_t pb2 = ((size_t)b*112 + j_eff)*576 + (size_t)(y*24 + x0 + i*4);
            ushort4 zb, hb, lb4;
            unsigned short h;
            zb.x = (znp[0]!=0.f)?(unsigned short)0x3F80:(unsigned short)0;
            zb.y = (znp[1]!=0.f)?(unsigned short)0x3F80:(unsigned short)0;
            zb.z = (znp[2]!=0.f)?(unsigned short)0x3F80:(unsigned short)0;
            zb.w = (znp[3]!=0.f)?(unsigned short)0x3F80:(unsigned short)0;
            h = f2bf(tnp[0]); hb.x = h; lb4.x = f2bf(tnp[0] - bf2f(h));
            h = f2bf(tnp[1]); hb.y = h; lb4.y = f2bf(tnp[1] - bf2f(h));
            h = f2bf(tnp[2]); hb.z = h; lb4.z = f2bf(tnp[2] - bf2f(h));
            h = f2bf(tnp[3]); hb.w = h; lb4.w = f2bf(tnp[3] - bf2f(h));
            *(ushort4*)(z4b + pb2) = zb;
            *(ushort4*)(tqh + pb2) = hb;
            *(ushort4*)(tql + pb2) = lb4;
        }
        if (jj == 0) spk0 = anyspk; else spk1 = anyspk;
    }
    if (spk0 && j0 < 100) atomicOr(&sjany[jp*2], 1);
    if (spk1 && j0+1 < 100) atomicOr(&sjany[jp*2+1], 1);
    __syncthreads();
    if (tid < 8 && jb0 + tid < 100) g_t[b*100 + jb0 + tid] = sjany[tid] ? 1.f : 0.f;
}

// ================= Launch C: MFMA STDP correlations (z=0) + w1-apply (z=1) =========
// z=0: grid (32 b, 15 cg), block 256 = 4 waves. Each block: one b, two c's (cg*2, cg*2+1).
// E2P[j,(c,p)] = sum_l z4[j,l] * unfold(tp2hi+tp2lo)[(c,p),l]   (per-b partial)
// E2M[j,(c,p)] = sum_l (tq2hi+tq2lo)[j,l] * unfold(z3)[(c,p),l]
// M = 112 (7 tiles of 16 j), per-c N = 2 tiles of 16 p (p<25 valid), K = 576 (18 ksteps of 32).
// LDS: 5 dx-shifted copies of each 28x28 pre image, row stride 24 -> B-frag = 1 ds_read_b128.
__global__ __launch_bounds__(256) void k_corr_mfma(
        const unsigned short* __restrict__ tp2hi, const unsigned short* __restrict__ tp2lo,
        const unsigned short* __restrict__ z3bf,
        const unsigned short* __restrict__ z4bf, const unsigned short* __restrict__ tq2hi,
        const unsigned short* __restrict__ tq2lo,
        const float* __restrict__ gflag, const int* __restrict__ cnz4,
        float* __restrict__ EPp, float* __restrict__ EMp,
        float* __restrict__ w1c, const float* __restrict__ part) {
    int tid = threadIdx.x;
    if (blockIdx.z == 1) {
        int lb = blockIdx.y*32 + blockIdx.x;
        if (lb >= 6) return;
        int e = lb*256 + tid;
        if (e < 1500) {
            int o = e / 50, r = e % 50, ch = r / 25, p = r % 25;
            float EpS = 0.f, EmS = 0.f;
            #pragma unroll
            for (int s = 0; s < 64; s++) {
                EpS += part[((size_t)(o*50 + p) << 6) + s];
                EmS += part[((size_t)(o*50 + 25 + p) << 6) + s];
            }
            float sign = (ch == 0) ? 1.0f : -1.0f;
            float w = w1c[e];
            float dwp = 0.004f * fmaxf(1.0f - w, 0.0f) * (sign * EpS);
            float dwm = 0.003f * fmaxf(w, 0.0f) * (sign * EmS);
            w1c[e] = fminf(fmaxf(w + dwp - dwm, 0.0f), 1.0f);
        }
        return;
    }
    int b = blockIdx.x, cg = blockIdx.y;
    // [cc:2][plane:3 (hi,lo,z3)][dx:5][672 u16] + zero block (704 u16)
    __shared__ __attribute__((aligned(16))) unsigned short sB[2*3*5*672 + 704];
    __shared__ float sG[100];
    __shared__ int sAnyI;
    if (tid == 0) sAnyI = 0;
    for (int i = tid; i < 704; i += 256) sB[20160 + i] = 0;
    if (tid < 100) {
        float gv = gflag[b*100 + tid];
        sG[tid] = gv;
        if (gv != 0.f) atomicOr(&sAnyI, 1);
    }
    int c0 = cg*2, c1 = cg*2 + 1;
    const int* cz0 = cnz4 + (b*30 + c0)*4;
    const int* cz1 = cnz4 + (b*30 + c1)*4;
    bool cA[2];
    cA[0] = (cz0[0] | cz0[1] | cz0[2] | cz0[3]) != 0;
    cA[1] = (cz1[0] | cz1[1] | cz1[2] | cz1[3]) != 0;
    __syncthreads();
    bool m0 = (sAnyI != 0);
    bool m1any = cA[0] || cA[1];
    // stage shifted pre-image planes
    for (int cc = 0; cc < 2; cc++) {
        int c = cg*2 + cc;
        for (int pl = 0; pl < 3; pl++) {
            bool need = (pl < 2) ? m0 : cA[cc];
            if (!need) continue;
            const unsigned short* src =
                ((pl == 0) ? tp2hi : (pl == 1) ? tp2lo : z3bf) + (size_t)(b*30 + c)*784;
            for (int idx = tid; idx < 784; idx += 256) {
                unsigned short v = src[idx];
                int r = idx / 28, col = idx - r*28;
                int base = ((cc*3 + pl)*5)*672 + r*24;
                #pragma unroll
                for (int dx = 0; dx < 5; dx++) {
                    int xx = col - dx;
                    if (xx >= 0 && xx < 24) sB[base + dx*672 + xx] = v;
                }
            }
        }
    }
    __syncthreads();
    int lane = tid & 63, w = tid >> 6;
    int mtv[2]; mtv[0] = w; mtv[1] = w + 4;
    bool mtok[2]; mtok[0] = true; mtok[1] = (w + 4) < 7;
    // per-Mtile mode0 gating (z4 row activity)
    bool m0mt[2];
    #pragma unroll
    for (int m = 0; m < 2; m++) {
        int jr = mtv[m]*16 + (lane & 15);
        float gv = (mtok[m] && jr < 100) ? sG[jr] : 0.f;
        m0mt[m] = m0 && (__any(gv != 0.f) != 0);
    }
    int g8 = (lane >> 4) * 8;
    size_t arow[2];
    #pragma unroll
    for (int m = 0; m < 2; m++)
        arow[m] = ((size_t)b*112 + (size_t)mtv[m]*16 + (lane & 15))*576 + g8;
    // B-frag byte offsets (per-lane constants); invalid p -> zero block at byte 40320
    int bOff[2][3][2];
    #pragma unroll
    for (int cc = 0; cc < 2; cc++)
        #pragma unroll
        for (int pl = 0; pl < 3; pl++)
            #pragma unroll
            for (int n = 0; n < 2; n++) {
                int p = n*16 + (lane & 15);
                int off;
                if (p < 25) {
                    int dy = p / 5, dx = p - dy*5;
                    off = (((cc*3 + pl)*5 + dx)*672 + dy*24)*2;
                } else off = 40320;
                bOff[cc][pl][n] = off;
            }
    f32x4 C0[2][2][2], C1[2][2][2];
    #pragma unroll
    for (int m = 0; m < 2; m++)
        #pragma unroll
        for (int cc = 0; cc < 2; cc++)
            #pragma unroll
            for (int n = 0; n < 2; n++) {
                C0[m][cc][n] = (f32x4){0.f, 0.f, 0.f, 0.f};
                C1[m][cc][n] = (f32x4){0.f, 0.f, 0.f, 0.f};
            }
    const char* sBb = (const char*)sB;
    #pragma unroll 1
    for (int ks = 0; ks < 18; ks++) {
        int kk = ks*32 + g8;
        int y = (kk * 2731) >> 16;              // kk / 24 for kk < 576
        int common = y*48 + ((kk - y*24) & 24)*2;  // byte offset within plane
        bfx8 a0[2], ah[2], al[2];
        #pragma unroll
        for (int m = 0; m < 2; m++) {
            size_t off = arow[m] + (size_t)ks*32;
            if (m0mt[m]) a0[m] = *(const bfx8*)(z4bf + off);
            if (mtok[m] && m1any) {
                ah[m] = *(const bfx8*)(tq2hi + off);
                al[m] = *(const bfx8*)(tq2lo + off);
            }
        }
        #pragma unroll
        for (int cc = 0; cc < 2; cc++) {
            #pragma unroll
            for (int n = 0; n < 2; n++) {
                if (m0) {
                    bfx8 Bh = *(const bfx8*)(sBb + bOff[cc][0][n] + common);
                    bfx8 Bl = *(const bfx8*)(sBb + bOff[cc][1][n] + common);
                    #pragma unroll
                    for (int m = 0; m < 2; m++) if (m0mt[m]) {
                        C0[m][cc][n] = __builtin_amdgcn_mfma_f32_16x16x32_bf16(a0[m], Bh, C0[m][cc][n], 0, 0, 0);
                        C0[m][cc][n] = __builtin_amdgcn_mfma_f32_16x16x32_bf16(a0[m], Bl, C0[m][cc][n], 0, 0, 0);
                    }
                }
                if (cA[cc]) {
                    bfx8 Bz = *(const bfx8*)(sBb + bOff[cc][2][n] + common);
                    #pragma unroll
                    for (int m = 0; m < 2; m++) if (mtok[m]) {
                        C1[m][cc][n] = __builtin_amdgcn_mfma_f32_16x16x32_bf16(ah[m], Bz, C1[m][cc][n], 0, 0, 0);
                        C1[m][cc][n] = __builtin_amdgcn_mfma_f32_16x16x32_bf16(al[m], Bz, C1[m][cc][n], 0, 0, 0);
                    }
                }
            }
        }
    }
    // write per-b partials; C/D layout: col = lane&15, row = (lane>>4)*4 + reg
    size_t eb = (size_t)b * 75000;
    #pragma unroll
    for (int m = 0; m < 2; m++) {
        if (!mtok[m]) continue;
        #pragma unroll
        for (int cc = 0; cc < 2; cc++) {
            int c = cg*2 + cc;
            #pragma unroll
            for (int n = 0; n < 2; n++) {
                int p = n*16 + (lane & 15);
                if (p >= 25) continue;
                #pragma unroll
                for (int q = 0; q < 4; q++) {
                    int j = mtv[m]*16 + (lane >> 4)*4 + q;
                    if (j < 100) {
                        size_t idx = eb + ((size_t)j*30 + c)*25 + p;
                        EPp[idx] = C0[m][cc][n][q];
                        EMp[idx] = C1[m][cc][n][q];
                    }
                }
            }
        }
    }
}

// ================= k_prep: build padded w2p from INPUT w2 =================
__global__ void k_prep(const float* __restrict__ w2, float* __restrict__ w2p) {
    int e = blockIdx.x*blockDim.x + threadIdx.x;
    if (e < 75000) {
        int j = e / 750, r = e % 750, c = r / 25, p = r % 25;
        w2p[((size_t)j*30 + c)*28 + p] = w2[e];
    }
}

// ================= k_fc1b: batched fc1, grid (500 n, 4 t-quarters) =================
__global__ __launch_bounds__(256) void k_fc1b(
        const float* __restrict__ g_all, const float* __restrict__ fcw,
        const float* __restrict__ fcb, float* __restrict__ h_all) {
    __shared__ float red[8][4];
    int n = blockIdx.x, by = blockIdx.y, tid = threadIdx.x;
    const float4* w4 = (const float4*)(fcw + (size_t)n*3200);
    float4 wreg[4];
    #pragma unroll
    for (int i = 0; i < 4; i++) {
        int k = tid + 256*i;
        if (k < 800) wreg[i] = w4[k];
    }
    float accs[8];
    #pragma unroll
    for (int tt = 0; tt < 8; tt++) accs[tt] = 0.f;
    #pragma unroll 1
    for (int tt = 0; tt < 8; tt++) {
        int t = by*8 + tt;
        const float4* g4 = (const float4*)(g_all + (size_t)t*3200);
        float a = 0.f;
        #pragma unroll
        for (int i = 0; i < 4; i++) {
            int k = tid + 256*i;
            if (k < 800) {
                float4 gv = g4[k];
                a = fmaf(gv.x, wreg[i].x, a);
                a = fmaf(gv.y, wreg[i].y, a);
                a = fmaf(gv.z, wreg[i].z, a);
                a = fmaf(gv.w, wreg[i].w, a);
            }
        }
        accs[tt] = a;
    }
    int lane = tid & 63, wid = tid >> 6;
    #pragma unroll
    for (int tt = 0; tt < 8; tt++) {
        float v = accs[tt];
        #pragma unroll
        for (int s = 32; s >= 1; s >>= 1) v += __shfl_down(v, s, 64);
        if (lane == 0) red[tt][wid] = v;
    }
    __syncthreads();
    if (tid < 8)
        h_all[(size_t)(by*8 + tid)*500 + n] =
            red[tid][0] + red[tid][1] + red[tid][2] + red[tid][3] + fcb[n];
}

// ================= k_head_all: LIF2 + LI readout =================
__global__ __launch_bounds__(640) void k_head_all(
        const float* __restrict__ h_all, const float* __restrict__ outw,
        float* __restrict__ out) {
    __shared__ float spk[500];
    __shared__ float vout[10];
    int tid = threadIdx.x;
    int wid = tid >> 6, lane = tid & 63;
    float v2r = 0.f, i2r = 0.f;
    float vor = 0.f, ior = 0.f;
    #pragma unroll 1
    for (int t = 0; t < 32; t++) {
        if (tid < 500) {
            float cur = i2r;
            float vd = v2r + DTMEM*(cur - v2r);
            float z = (vd > 1.0f) ? 1.0f : 0.0f;
            v2r = (1.0f - z)*vd;
            i2r = (cur - DTSYN*cur) + h_all[t*500 + tid];
            spk[tid] = z;
        }
        __syncthreads();
        float acc = 0.f;
        for (int n = lane; n < 500; n += 64)
            acc = fmaf(spk[n], outw[wid*500 + n], acc);
        #pragma unroll
        for (int s = 32; s >= 1; s >>= 1) acc += __shfl_down(acc, s, 64);
        if (lane == 0) {
            float ij = ior + acc;
            float vn = vor + DTMEM*(ij - vor);
            ior = ij - DTSYN*ij;
            vor = vn;
            vout[wid] = vn;
        }
        __syncthreads();
        if (tid < 320) out[(size_t)t*320 + tid] = vout[tid % 10];
        __syncthreads();
    }
}

// ---------------- launcher ----------------
extern "C" void kernel_launch(void* const* d_in, const int* in_sizes, int n_in,
                              void* d_out, int out_size, void* d_ws, size_t ws_size,
                              hipStream_t stream) {
    const float* x    = (const float*)d_in[0];
    const float* b1   = (const float*)d_in[1];
    const float* b2   = (const float*)d_in[2];
    const float* w1   = (const float*)d_in[3];
    const float* w2   = (const float*)d_in[4];
    const float* fcw  = (const float*)d_in[5];
    const float* fcb  = (const float*)d_in[6];
    const float* outw = (const float*)d_in[7];
    float* ws  = (float*)d_ws;
    float* out = (float*)d_out;

    DK dk;
    {
        float g1[25], g2[25], s1 = 0.f, s2 = 0.f;
        for (int i = 0; i < 5; i++)
            for (int j = 0; j < 5; j++) {
                float ai = (float)(i - 2), aj = (float)(j - 2);
                float r2 = ai*ai + aj*aj;
                g1[i*5+j] = expf(-r2/2.0f);
                g2[i*5+j] = expf(-r2/8.0f);
                s1 += g1[i*5+j]; s2 += g2[i*5+j];
            }
        for (int k = 0; k < 25; k++) dk.v[k] = g1[k]/s1 - g2[k]/s2;
    }

    hipMemcpyAsync(ws + OW1, w1, 1500*sizeof(float), hipMemcpyDeviceToDevice, stream);
    hipMemsetAsync(ws + OV0, 0, (OZEND - OV0)*sizeof(float), stream);
    k_prep<<<294, 256, 0, stream>>>(w2, ws + OW2P);

    for (int t = 0; t < T; t++) {
        const float* tp1r = ws + ((t & 1) ? OTP1B : OTP1A);
        float*       tp1w = ws + ((t & 1) ? OTP1A : OTP1B);
        k_front<<<dim3(8, 64, 2), 448, 0, stream>>>(
            x, b1, b2, ws+OW1, tp1r, tp1w, ws+OV0, ws+OI0, ws+OTQ1,
            ws+OZ3, ws+OTP2, ws+OP1, (int*)(ws+OCNZ), ws+OW2P,
            (unsigned short*)(ws+OPHI), (unsigned short*)(ws+OPLO),
            (unsigned short*)(ws+OPZ3),
            ws+OEPP, ws+OEMP, dk, t);
        k_conv2lif<<<dim3(13, 32), 192, 0, stream>>>(
            ws+OW2P, ws+OZ3, (int*)(ws+OCNZ),
            ws+OV1S, ws+OI1S, ws+OTQ2S,
            (unsigned short*)(ws+OQZ4), (unsigned short*)(ws+OQHI),
            (unsigned short*)(ws+OQLO),
            ws+OG + (size_t)t*3200);
        k_corr_mfma<<<dim3(32, 15, 2), 256, 0, stream>>>(
            (const unsigned short*)(ws+OPHI), (const unsigned short*)(ws+OPLO),
            (const unsigned short*)(ws+OPZ3),
            (const unsigned short*)(ws+OQZ4), (const unsigned short*)(ws+OQHI),
            (const unsigned short*)(ws+OQLO),
            ws+OG + (size_t)t*3200, (const int*)(ws+OCNZ),
            ws+OEPP, ws+OEMP, ws+OW1, ws+OP1);
    }
    k_fc1b<<<dim3(500, 4), 256, 0, stream>>>(ws+OG, fcw, fcb, ws+OHH);
    k_head_all<<<1, 640, 0, stream>>>(ws+OHH, outw, out);
}

// Round 2
// 1545.369 us; speedup vs baseline: 1.2925x; 1.1697x over previous
//
#include <hip/hip_runtime.h>
#include <math.h>

// ---------------- constants ----------------
#define DTMEM 0.1f   // DT*TAU_MEM_INV
#define DTSYN 0.2f   // DT*TAU_SYN_INV
#define DTTR  0.02f  // DT*TAU_PRE_INV == DT*TAU_POST_INV

static constexpr int B = 32, T = 32;
static constexpr int HD = 60, H1 = 56, HP = 28, H2 = 24;
static constexpr int LD  = HD*HD;   // 3600
static constexpr int L1N = H1*H1;   // 3136
static constexpr int LP  = HP*HP;   // 784
static constexpr int L2N = H2*H2;   // 576

// lif0 state: thread-slot-major [b][og:8][yh:2][i:7][tid:448] float2
static constexpr size_t SST  = (size_t)B*8*2*7*448*2;          // floats (=3,211,264)
// conv2 state: thread-slot-major [b][jg:13][slot:6][tid:192] float4
static constexpr size_t SST2 = (size_t)B*13*6*192*4;           // floats (=1,916,928)

// float offsets: zero region is [OV0, OZEND)
static constexpr size_t OW1   = 0;                             // 1500
static constexpr size_t OV0   = OW1 + 1500;
static constexpr size_t OI0   = OV0   + SST;
static constexpr size_t OTQ1  = OI0   + SST;
static constexpr size_t OTP1A = OTQ1  + SST;                   // [B,60,60]
static constexpr size_t OTP2  = OTP1A + (size_t)B*LD;          // [B,30,28,28]
static constexpr size_t OV1S  = OTP2  + (size_t)B*30*LP;
static constexpr size_t OI1S  = OV1S  + SST2;
static constexpr size_t OTQ2S = OI1S  + SST2;
static constexpr size_t OZEND = OTQ2S + SST2;                  // end of zero region
static constexpr size_t OTP1B = OZEND;                         // [B,60,60] pong
static constexpr size_t OZ3   = OTP1B + (size_t)B*LD;          // [B,30,28,28]
static constexpr size_t OZ4S  = OZ3   + (size_t)B*30*LP;      // (unused, layout keep)
static constexpr size_t OE2P  = OZ4S  + SST2;                  // (unused)
static constexpr size_t OE2M  = OE2P  + 75000;                 // (unused)
static constexpr size_t OP1   = OE2M  + 75000;                 // [30][50][64]
static constexpr size_t OG    = OP1   + 96000;                 // [T][3200]
static constexpr size_t OHH   = OG    + (size_t)T*3200;        // [T][500]
static constexpr size_t OW2P  = OHH   + (size_t)T*500;         // [100][30][28]
static constexpr size_t OCNZ  = OW2P  + 84000;                 // int[960][4]
static constexpr size_t OTOT  = OCNZ  + 3840;
// MFMA correlation buffers:
static constexpr size_t OEPP  = OTOT;                          // E2P partials [32][75000] f32
static constexpr size_t OEMP  = OEPP + (size_t)B*75000;        // E2M partials [32][75000] f32
static constexpr size_t OPHI  = OEMP + (size_t)B*75000;        // tp2 hi plane [B][30][784] u16
static constexpr size_t OPLO  = OPHI + 376320;                 // tp2 lo plane
static constexpr size_t OPZ3  = OPLO + 376320;                 // z3 bf16 plane
static constexpr size_t OQZ4  = OPZ3 + 376320;                 // z4 bf16 [B][112][576] u16
static constexpr size_t OQHI  = OQZ4 + 1032192;                // tq2 hi plane
static constexpr size_t OQLO  = OQHI + 1032192;                // tq2 lo plane
static constexpr size_t OTOT2 = OQLO + 1032192;
// sticky zero-tracking flags:
static constexpr size_t OQZF  = OTOT2;                         // int[512]  tq1-zero per (b,og,yh)
static constexpr size_t OPZF  = OQZF + 512;                    // int[960]  plane-zero per (b,o)
static constexpr size_t OSZF  = OPZF + 960;                    // int[416]  conv2-state-zero per (b,jg)
static constexpr size_t OEAF  = OSZF + 416;                    // int[480]  E-active per (b,cg), per-step
static constexpr size_t OTOT3 = OEAF + 480;

struct DK { float v[25]; };

typedef __attribute__((ext_vector_type(8))) short bfx8;
typedef __attribute__((ext_vector_type(4))) float f32x4;

static __device__ __forceinline__ unsigned short f2bf(float f) {
    unsigned u = __float_as_uint(f);
    return (unsigned short)((u + 0x7FFFu + ((u >> 16) & 1u)) >> 16);
}
static __device__ __forceinline__ float bf2f(unsigned short h) {
    return __uint_as_float(((unsigned)h) << 16);
}

// ================= Launch A: z=0 front(t) y-half blocks; z=1 w2-apply(t-1) =========
// front: grid (8 og, 64 = b*2+yh, 2), block 448 = (oo:4, xq:4, y:28).
__global__ __launch_bounds__(448) void k_front(
        const float* __restrict__ x, const float* __restrict__ b1,
        const float* __restrict__ b2, const float* __restrict__ w1c,
        const float* __restrict__ tp1r, float* __restrict__ tp1w,
        float* __restrict__ v0, float* __restrict__ i0, float* __restrict__ tq1,
        float* __restrict__ z3, float* __restrict__ tp2,
        float* __restrict__ part, int* __restrict__ cnz4,
        float* __restrict__ w2p,
        unsigned short* __restrict__ uhi, unsigned short* __restrict__ ulo,
        unsigned short* __restrict__ uz3,
        const float* __restrict__ EPp, const float* __restrict__ EMp,
        int* __restrict__ qzf, const int* __restrict__ pzf,
        const int* __restrict__ eactf,
        DK dk, int t) {
    if (blockIdx.z == 1) {
        if (t == 0) return;
        int lb = blockIdx.y*8 + blockIdx.x;
        int e = lb*448 + threadIdx.x;
        if (e < 75000) {
            int j = e / 750, r = e % 750, c = r / 25, p = r % 25;
            int cg = c >> 1;
            float ep = 0.f, em = 0.f;
            int anyf = 0;
            #pragma unroll 4
            for (int bb = 0; bb < 32; bb++) {
                if (eactf[bb*15 + cg]) {
                    anyf = 1;
                    ep += EPp[(size_t)bb*75000 + e];
                    em += EMp[(size_t)bb*75000 + e];
                }
            }
            if (anyf) {
                size_t f = ((size_t)j*30 + c)*28 + p;
                float w = w2p[f];
                float dwp = 0.004f * fmaxf(1.0f - w, 0.0f) * ep;
                float dwm = 0.003f * fmaxf(w, 0.0f) * em;
                w2p[f] = fminf(fmaxf(w + dwp - dwm, 0.0f), 1.0f);
            }
        }
        return;
    }
    __shared__ __attribute__((aligned(16))) float xsh[36*64];   // x rows [y0, y0+36)
    __shared__ __attribute__((aligned(16))) float zsh[32*60];   // DoG rows [y0, y0+32)
    __shared__ __attribute__((aligned(16))) float tsh[32*60];   // tp1 rows [y0, y0+32)
    __shared__ float red[700];                                   // 7 waves x 100
    __shared__ float wd[100];
    __shared__ int sflags[8];
    int og = blockIdx.x, by = blockIdx.y, tid = threadIdx.x;
    int b = by >> 1, yh = by & 1, y0 = yh*28;
    int qzOld = qzf[(b*8 + og)*2 + yh];
    {
        const float4* xs = (const float4*)(x + ((size_t)t*B + b)*4096) + y0*16;
        const float4* ts = (const float4*)(tp1r + (size_t)b*LD) + y0*15;
        for (int i = tid; i < 576; i += 448) ((float4*)xsh)[i] = xs[i];
        for (int i = tid; i < 480; i += 448) ((float4*)tsh)[i] = ts[i];
    }
    if (tid < 100) {
        int oo2 = tid / 25, p = tid % 25;
        int o2 = og*4 + oo2; if (o2 > 29) o2 = 29;
        wd[tid] = w1c[o2*50 + p] - w1c[o2*50 + 25 + p];
    }
    if (tid < 8) sflags[tid] = 0;
    __syncthreads();
    float bias = b1[0] - b2[0];
    // DoG + tp1 trace on local rows (og==0 persists tp1; overlap rows identical)
    for (int idx = tid; idx < 1920; idx += 448) {
        int lr = idx / 60, c = idx % 60;
        float a = 0.f;
        #pragma unroll
        for (int kh = 0; kh < 5; kh++)
            #pragma unroll
            for (int kw = 0; kw < 5; kw++)
                a = fmaf(dk.v[kh*5+kw], xsh[(lr+kh)*64 + c + kw], a);
        float zv = a + bias;
        zsh[idx] = zv;
        float tp = tsh[idx];
        tp = tp + DTTR*(zv - tp);
        tsh[idx] = tp;
        if (og == 0) tp1w[(size_t)b*LD + (y0 + lr)*60 + c] = tp;
    }
    __syncthreads();
    int oo = tid & 3, xq = (tid >> 2) & 3, y = tid >> 4;   // y local [0,28)
    int o = og*4 + oo, x0 = xq*14;
    bool valid = (o < 30);
    float zn[14], tn[14];
    float zs = 0.f, qs = 0.f;
    bool anym = false;
    if (valid) {
        float acc[14];
        #pragma unroll
        for (int k = 0; k < 14; k++) acc[k] = 0.f;
        #pragma unroll
        for (int kh = 0; kh < 5; kh++) {
            float rr[18];
            const float2* r2 = (const float2*)&zsh[(y+kh)*HD + x0];
            #pragma unroll
            for (int i = 0; i < 9; i++) ((float2*)rr)[i] = r2[i];
            #pragma unroll
            for (int kw = 0; kw < 5; kw++) {
                float w = wd[oo*25 + kh*5 + kw];
                #pragma unroll
                for (int k = 0; k < 14; k++) acc[k] = fmaf(w, rr[k+kw], acc[k]);
            }
        }
        // LIF0 + tq1 in slot-major float2 (coalesced); tq1 r+w gated by sticky zero flag
        float2* v0p = (float2*)v0;
        float2* i0p = (float2*)i0;
        float2* tq1p = (float2*)tq1;
        size_t sb = ((size_t)((b*8 + og)*2 + yh)*7)*448 + tid;
        #pragma unroll
        for (int i = 0; i < 7; i++) {
            float2 v2 = v0p[sb + (size_t)i*448];
            float2 c2 = i0p[sb + (size_t)i*448];
            float2 t2;
            if (qzOld) { t2.x = 0.f; t2.y = 0.f; }
            else t2 = tq1p[sb + (size_t)i*448];
            float2 vn, in, tn2;
            #pragma unroll
            for (int k = 0; k < 2; k++) {
                int e = i*2 + k;
                float vv = k ? v2.y : v2.x, cc = k ? c2.y : c2.x, tt = k ? t2.y : t2.x;
                float vd = vv + DTMEM*(cc - vv);
                float z = (vd > 15.0f) ? 1.0f : 0.0f;
                float vo = (1.0f - z)*vd;
                float io_ = (cc - DTSYN*cc) + acc[e];
                float tq = tt + DTTR*(z - tt);
                if (k) { vn.y = vo; in.y = io_; tn2.y = tq; } else { vn.x = vo; in.x = io_; tn2.x = tq; }
                zn[e] = z; tn[e] = tq;
            }
            v0p[sb + (size_t)i*448] = vn;
            i0p[sb + (size_t)i*448] = in;
            if (!qzOld || (zn[i*2] != 0.f) || (zn[i*2+1] != 0.f))
                tq1p[sb + (size_t)i*448] = tn2;
        }
        #pragma unroll
        for (int k = 0; k < 14; k++) { zs += zn[k]; qs += tn[k]; }
        float mx[7];
        #pragma unroll
        for (int k = 0; k < 7; k++) mx[k] = fmaxf(zn[2*k], zn[2*k+1]);
        #pragma unroll
        for (int k = 0; k < 7; k++) {
            float pm = __shfl_xor(mx[k], 16, 64);   // y-partner (y^1)
            mx[k] = fmaxf(mx[k], pm);
        }
        if ((y & 1) == 0) {
            int pzOld = pzf[b*30 + o];
            int py = yh*14 + (y >> 1);
            size_t pb = ((size_t)(b*30 + o)*HP + py)*HP + xq*7;
            #pragma unroll
            for (int k = 0; k < 7; k++) {
                float m = mx[k];
                anym = anym || (m != 0.f);
                if (!pzOld || m != 0.f) {
                    z3[pb + k] = m;
                    float tpv = pzOld ? 0.f : tp2[pb + k];
                    float tnew = tpv + DTTR*(m - tpv);
                    tp2[pb + k] = tnew;
                    unsigned short h = f2bf(tnew);
                    uhi[pb + k] = h;
                    ulo[pb + k] = f2bf(tnew - bf2f(h));
                    uz3[pb + k] = (m != 0.f) ? (unsigned short)0x3F80 : (unsigned short)0;
                }
            }
        }
    }
    if (anym) atomicOr(&sflags[oo*2 + (xq >> 1)], 1);
    int lane = tid & 63, wave = tid >> 6;
    // pass 1: minus correlation (unfold(z0) x tq1_new)
    {
        float a[25];
        #pragma unroll
        for (int p = 0; p < 25; p++) a[p] = 0.f;
        if (valid && qs != 0.f) {
            #pragma unroll
            for (int kh = 0; kh < 5; kh++) {
                float rr[18];
                const float2* r2 = (const float2*)&zsh[(y+kh)*HD + x0];
                #pragma unroll
                for (int i = 0; i < 9; i++) ((float2*)rr)[i] = r2[i];
                #pragma unroll
                for (int kw = 0; kw < 5; kw++)
                    #pragma unroll
                    for (int k = 0; k < 14; k++)
                        a[kh*5+kw] = fmaf(rr[k+kw], tn[k], a[kh*5+kw]);
            }
        }
        #pragma unroll
        for (int q = 0; q < 25; q++) {
            float v = a[q];
            v += __shfl_xor(v, 4, 64);
            v += __shfl_xor(v, 8, 64);
            v += __shfl_xor(v, 16, 64);
            v += __shfl_xor(v, 32, 64);
            if (lane < 4) red[wave*100 + lane*25 + q] = v;
        }
    }
    __syncthreads();
    if (tid < 100) {
        int oo2 = tid / 25, q = tid % 25;
        float s = 0.f;
        #pragma unroll
        for (int w = 0; w < 7; w++) s += red[w*100 + oo2*25 + q];
        int o2 = og*4 + oo2;
        if (o2 < 30) part[((size_t)(o2*50 + 25 + q) << 6) + b*2 + yh] = s;
    }
    if (tid < 8) {
        int o2 = og*4 + (tid >> 1);
        if (o2 < 30) cnz4[(b*30 + o2)*4 + yh*2 + (tid & 1)] = sflags[tid];
    }
    if (tid == 0 && qzOld) {
        if (sflags[0]|sflags[1]|sflags[2]|sflags[3]|
            sflags[4]|sflags[5]|sflags[6]|sflags[7])
            qzf[(b*8 + og)*2 + yh] = 0;
    }
    __syncthreads();
    // pass 2: plus correlation (unfold(tp1_new) x z2)
    {
        float a[25];
        #pragma unroll
        for (int p = 0; p < 25; p++) a[p] = 0.f;
        if (valid && zs != 0.f) {
            #pragma unroll
            for (int kh = 0; kh < 5; kh++) {
                float rr[18];
                const float2* r2 = (const float2*)&tsh[(y+kh)*HD + x0];
                #pragma unroll
                for (int i = 0; i < 9; i++) ((float2*)rr)[i] = r2[i];
                #pragma unroll
                for (int kw = 0; kw < 5; kw++)
                    #pragma unroll
                    for (int k = 0; k < 14; k++)
                        a[kh*5+kw] = fmaf(rr[k+kw], zn[k], a[kh*5+kw]);
            }
        }
        #pragma unroll
        for (int q = 0; q < 25; q++) {
            float v = a[q];
            v += __shfl_xor(v, 4, 64);
            v += __shfl_xor(v, 8, 64);
            v += __shfl_xor(v, 16, 64);
            v += __shfl_xor(v, 32, 64);
            if (lane < 4) red[wave*100 + lane*25 + q] = v;
        }
    }
    __syncthreads();
    if (tid < 100) {
        int oo2 = tid / 25, q = tid % 25;
        float s = 0.f;
        #pragma unroll
        for (int w = 0; w < 7; w++) s += red[w*100 + oo2*25 + q];
        int o2 = og*4 + oo2;
        if (o2 < 30) part[((size_t)(o2*50 + q) << 6) + b*2 + yh] = s;
    }
}

// ================= Launch B: conv2 + LIF1 + tq2 + g (slot-major state) =========
// grid (13 jg, 32 b), block 192 = (jp:4, xh:2, y:24).
__global__ __launch_bounds__(192) void k_conv2lif(
        const float* __restrict__ w2p, const float* __restrict__ z3,
        const int* __restrict__ cnz4,
        float* __restrict__ v1s, float* __restrict__ i1s,
        float* __restrict__ tq2s,
        unsigned short* __restrict__ z4b, unsigned short* __restrict__ tqh,
        unsigned short* __restrict__ tql,
        float* __restrict__ g_t,
        int* __restrict__ szf, int* __restrict__ pzf) {
    __shared__ __attribute__((aligned(16))) float spre[LP];
    __shared__ int sjany[8];
    __shared__ int sany;
    int jg = blockIdx.x, b = blockIdx.y, tid = threadIdx.x;
    int jb0 = jg*8;
    if (tid < 8) sjany[tid] = 0;
    if (tid == 0) sany = 0;
    __syncthreads();
    if (tid < 120 && cnz4[b*120 + tid]) atomicOr(&sany, 1);
    __syncthreads();
    // sticky plane-zero update (one block per b)
    if (jg == 0 && tid < 30) {
        const int* cz = cnz4 + (b*30 + tid)*4;
        if ((cz[0] | cz[1] | cz[2] | cz[3]) != 0) pzf[b*30 + tid] = 0;
    }
    int szv = szf[b*13 + jg];
    if (szv && !sany) {
        // state provably all-zero and no input: planes/state stay zero in memory
        if (tid < 8 && jb0 + tid < 100) g_t[b*100 + jb0 + tid] = 0.f;
        return;
    }
    int jp = tid & 3;
    int j0 = jb0 + jp*2;
    int y = tid >> 3, x0 = ((tid >> 2) & 1)*12;
    int ja = (j0 < 100) ? j0 : 99;
    int jbb = (j0+1 < 100) ? j0+1 : 99;
    float acc0[12], acc1[12];
    #pragma unroll
    for (int xq = 0; xq < 12; xq++) { acc0[xq] = 0.f; acc1[xq] = 0.f; }
    #pragma unroll 1
    for (int c = 0; c < 30; c++) {
        const int* cz = cnz4 + (b*30 + c)*4;
        bool act = (cz[0] | cz[1] | cz[2] | cz[3]) != 0;
        __syncthreads();
        if (act) {
            const float4* src = (const float4*)(z3 + (size_t)(b*30 + c)*LP);
            float4* dst = (float4*)spre;
            for (int i = tid; i < 196; i += 192) dst[i] = src[i];
        }
        __syncthreads();
        if (!act) continue;
        float wa[28], wb[28];
        #pragma unroll
        for (int i = 0; i < 7; i++) {
            ((float4*)wa)[i] = ((const float4*)(w2p + ((size_t)ja*30 + c)*28))[i];
            ((float4*)wb)[i] = ((const float4*)(w2p + ((size_t)jbb*30 + c)*28))[i];
        }
        #pragma unroll
        for (int kh = 0; kh < 5; kh++) {
            float rr[16];
            const float4* r4 = (const float4*)&spre[(y+kh)*HP + x0];
            #pragma unroll
            for (int i = 0; i < 4; i++) ((float4*)rr)[i] = r4[i];
            #pragma unroll
            for (int kw = 0; kw < 5; kw++) {
                float w0 = wa[kh*5+kw], w1 = wb[kh*5+kw];
                #pragma unroll
                for (int xq = 0; xq < 12; xq++) {
                    acc0[xq] = fmaf(w0, rr[xq+kw], acc0[xq]);
                    acc1[xq] = fmaf(w1, rr[xq+kw], acc1[xq]);
                }
            }
        }
    }
    float4* v1p = (float4*)v1s; float4* i1p = (float4*)i1s;
    float4* t2p = (float4*)tq2s;
    size_t sb2 = ((size_t)(b*13 + jg)*6)*192 + tid;
    bool spk0 = false, spk1 = false;
    #pragma unroll
    for (int jj = 0; jj < 2; jj++) {
        bool anyspk = false;
        int j_eff = jj ? jbb : ja;
        #pragma unroll
        for (int i = 0; i < 3; i++) {
            size_t si = sb2 + (size_t)(jj*3 + i)*192;
            float4 v4 = v1p[si];
            float4 c4 = i1p[si];
            float4 t4 = t2p[si];
            float4 vn, in, zn, tn;
            float* vp=(float*)&v4; float* cp=(float*)&c4; float* tp=(float*)&t4;
            float* vnp=(float*)&vn; float* inp=(float*)&in; float* znp=(float*)&zn; float* tnp=(float*)&tn;
            #pragma unroll
            for (int k = 0; k < 4; k++) {
                float a = jj ? acc1[i*4+k] : acc0[i*4+k];
                float vd = vp[k] + DTMEM*(cp[k] - vp[k]);
                float z = (vd > 10.0f) ? 1.0f : 0.0f;
                vnp[k] = (1.0f - z)*vd;
                inp[k] = (cp[k] - DTSYN*cp[k]) + 10.0f*a;
                znp[k] = z;
                tnp[k] = tp[k] + DTTR*(z - tp[k]);
                anyspk = anyspk || (z != 0.f);
            }
            v1p[si] = vn;
            i1p[si] = in;
            t2p[si] = tn;
            // bf16 planes [b][j:112][l:576], l = y*24 + x0 + i*4 + k
            size_t pb2 = ((size_t)b*112 + j_eff)*576 + (size_t)(y*24 + x0 + i*4);
            ushort4 zb, hb, lb4;
            unsigned short h;
            zb.x = (znp[0]!=0.f)?(unsigned short)0x3F80:(unsigned short)0;
            zb.y = (znp[1]!=0.f)?(unsigned short)0x3F80:(unsigned short)0;
            zb.z = (znp[2]!=0.f)?(unsigned short)0x3F80:(unsigned short)0;
            zb.w = (znp[3]!=0.f)?(unsigned short)0x3F80:(unsigned short)0;
            h = f2bf(tnp[0]); hb.x = h; lb4.x = f2bf(tnp[0] - bf2f(h));
            h = f2bf(tnp[1]); hb.y = h; lb4.y = f2bf(tnp[1] - bf2f(h));
            h = f2bf(tnp[2]); hb.z = h; lb4.z = f2bf(tnp[2] - bf2f(h));
            h = f2bf(tnp[3]); hb.w = h; lb4.w = f2bf(tnp[3] - bf2f(h));
            *(ushort4*)(z4b + pb2) = zb;
            *(ushort4*)(tqh + pb2) = hb;
            *(ushort4*)(tql + pb2) = lb4;
        }
        if (jj == 0) spk0 = anyspk; else spk1 = anyspk;
    }
    if (spk0 && j0 < 100) atomicOr(&sjany[jp*2], 1);
    if (spk1 && j0+1 < 100) atomicOr(&sjany[jp*2+1], 1);
    __syncthreads();
    if (tid < 8 && jb0 + tid < 100) g_t[b*100 + jb0 + tid] = sjany[tid] ? 1.f : 0.f;
    if (tid == 0 && szv) szf[b*13 + jg] = 0;   // state may now be nonzero
}

// ================= Launch C: MFMA STDP correlations (z=0) + w1-apply (z=1) =========
__global__ __launch_bounds__(256) void k_corr_mfma(
        const unsigned short* __restrict__ tp2hi, const unsigned short* __restrict__ tp2lo,
        const unsigned short* __restrict__ z3bf,
        const unsigned short* __restrict__ z4bf, const unsigned short* __restrict__ tq2hi,
        const unsigned short* __restrict__ tq2lo,
        const float* __restrict__ gflag, const int* __restrict__ cnz4,
        float* __restrict__ EPp, float* __restrict__ EMp,
        float* __restrict__ w1c, const float* __restrict__ part,
        int* __restrict__ eact) {
    int tid = threadIdx.x;
    if (blockIdx.z == 1) {
        int lb = blockIdx.y*32 + blockIdx.x;
        if (lb >= 6) return;
        int e = lb*256 + tid;
        if (e < 1500) {
            int o = e / 50, r = e % 50, ch = r / 25, p = r % 25;
            float EpS = 0.f, EmS = 0.f;
            #pragma unroll
            for (int s = 0; s < 64; s++) {
                EpS += part[((size_t)(o*50 + p) << 6) + s];
                EmS += part[((size_t)(o*50 + 25 + p) << 6) + s];
            }
            float sign = (ch == 0) ? 1.0f : -1.0f;
            float w = w1c[e];
            float dwp = 0.004f * fmaxf(1.0f - w, 0.0f) * (sign * EpS);
            float dwm = 0.003f * fmaxf(w, 0.0f) * (sign * EmS);
            w1c[e] = fminf(fmaxf(w + dwp - dwm, 0.0f), 1.0f);
        }
        return;
    }
    int b = blockIdx.x, cg = blockIdx.y;
    // [cc:2][plane:3 (hi,lo,z3)][dx:5][672 u16] + zero block (704 u16)
    __shared__ __attribute__((aligned(16))) unsigned short sB[2*3*5*672 + 704];
    __shared__ float sG[100];
    __shared__ int sAnyI;
    if (tid == 0) sAnyI = 0;
    for (int i = tid; i < 704; i += 256) sB[20160 + i] = 0;
    if (tid < 100) {
        float gv = gflag[b*100 + tid];
        sG[tid] = gv;
        if (gv != 0.f) atomicOr(&sAnyI, 1);
    }
    int c0 = cg*2, c1 = cg*2 + 1;
    const int* cz0 = cnz4 + (b*30 + c0)*4;
    const int* cz1 = cnz4 + (b*30 + c1)*4;
    bool cA[2];
    cA[0] = (cz0[0] | cz0[1] | cz0[2] | cz0[3]) != 0;
    cA[1] = (cz1[0] | cz1[1] | cz1[2] | cz1[3]) != 0;
    __syncthreads();
    bool m0 = (sAnyI != 0);
    bool m1any = cA[0] || cA[1];
    bool activeB = m0 || m1any;
    if (tid == 0) eact[b*15 + cg] = activeB ? 1 : 0;
    if (!activeB) return;   // E partials not written; w2-apply skips via eact
    // stage shifted pre-image planes
    for (int cc = 0; cc < 2; cc++) {
        int c = cg*2 + cc;
        for (int pl = 0; pl < 3; pl++) {
            bool need = (pl < 2) ? m0 : cA[cc];
            if (!need) continue;
            const unsigned short* src =
                ((pl == 0) ? tp2hi : (pl == 1) ? tp2lo : z3bf) + (size_t)(b*30 + c)*784;
            for (int idx = tid; idx < 784; idx += 256) {
                unsigned short v = src[idx];
                int r = idx / 28, col = idx - r*28;
                int base = ((cc*3 + pl)*5)*672 + r*24;
                #pragma unroll
                for (int dx = 0; dx < 5; dx++) {
                    int xx = col - dx;
                    if (xx >= 0 && xx < 24) sB[base + dx*672 + xx] = v;
                }
            }
        }
    }
    __syncthreads();
    int lane = tid & 63, w = tid >> 6;
    int mtv[2]; mtv[0] = w; mtv[1] = w + 4;
    bool mtok[2]; mtok[0] = true; mtok[1] = (w + 4) < 7;
    // per-Mtile mode0 gating (z4 row activity)
    bool m0mt[2];
    #pragma unroll
    for (int m = 0; m < 2; m++) {
        int jr = mtv[m]*16 + (lane & 15);
        float gv = (mtok[m] && jr < 100) ? sG[jr] : 0.f;
        m0mt[m] = m0 && (__any(gv != 0.f) != 0);
    }
    int g8 = (lane >> 4) * 8;
    size_t arow[2];
    #pragma unroll
    for (int m = 0; m < 2; m++)
        arow[m] = ((size_t)b*112 + (size_t)mtv[m]*16 + (lane & 15))*576 + g8;
    // B-frag byte offsets (per-lane constants); invalid p -> zero block at byte 40320
    int bOff[2][3][2];
    #pragma unroll
    for (int cc = 0; cc < 2; cc++)
        #pragma unroll
        for (int pl = 0; pl < 3; pl++)
            #pragma unroll
            for (int n = 0; n < 2; n++) {
                int p = n*16 + (lane & 15);
                int off;
                if (p < 25) {
                    int dy = p / 5, dx = p - dy*5;
                    off = (((cc*3 + pl)*5 + dx)*672 + dy*24)*2;
                } else off = 40320;
                bOff[cc][pl][n] = off;
            }
    f32x4 C0[2][2][2], C1[2][2][2];
    #pragma unroll
    for (int m = 0; m < 2; m++)
        #pragma unroll
        for (int cc = 0; cc < 2; cc++)
            #pragma unroll
            for (int n = 0; n < 2; n++) {
                C0[m][cc][n] = (f32x4){0.f, 0.f, 0.f, 0.f};
                C1[m][cc][n] = (f32x4){0.f, 0.f, 0.f, 0.f};
            }
    const char* sBb = (const char*)sB;
    #pragma unroll 1
    for (int ks = 0; ks < 18; ks++) {
        int kk = ks*32 + g8;
        int y = (kk * 2731) >> 16;              // kk / 24 for kk < 576
        int common = y*48 + ((kk - y*24) & 24)*2;  // byte offset within plane
        bfx8 a0[2], ah[2], al[2];
        #pragma unroll
        for (int m = 0; m < 2; m++) {
            size_t off = arow[m] + (size_t)ks*32;
            if (m0mt[m]) a0[m] = *(const bfx8*)(z4bf + off);
            if (mtok[m] && m1any) {
                ah[m] = *(const bfx8*)(tq2hi + off);
                al[m] = *(const bfx8*)(tq2lo + off);
            }
        }
        #pragma unroll
        for (int cc = 0; cc < 2; cc++) {
            #pragma unroll
            for (int n = 0; n < 2; n++) {
                if (m0) {
                    bfx8 Bh = *(const bfx8*)(sBb + bOff[cc][0][n] + common);
                    bfx8 Bl = *(const bfx8*)(sBb + bOff[cc][1][n] + common);
                    #pragma unroll
                    for (int m = 0; m < 2; m++) if (m0mt[m]) {
                        C0[m][cc][n] = __builtin_amdgcn_mfma_f32_16x16x32_bf16(a0[m], Bh, C0[m][cc][n], 0, 0, 0);
                        C0[m][cc][n] = __builtin_amdgcn_mfma_f32_16x16x32_bf16(a0[m], Bl, C0[m][cc][n], 0, 0, 0);
                    }
                }
                if (cA[cc]) {
                    bfx8 Bz = *(const bfx8*)(sBb + bOff[cc][2][n] + common);
                    #pragma unroll
                    for (int m = 0; m < 2; m++) if (mtok[m]) {
                        C1[m][cc][n] = __builtin_amdgcn_mfma_f32_16x16x32_bf16(ah[m], Bz, C1[m][cc][n], 0, 0, 0);
                        C1[m][cc][n] = __builtin_amdgcn_mfma_f32_16x16x32_bf16(al[m], Bz, C1[m][cc][n], 0, 0, 0);
                    }
                }
            }
        }
    }
    // write per-b partials; C/D layout: col = lane&15, row = (lane>>4)*4 + reg
    size_t eb = (size_t)b * 75000;
    #pragma unroll
    for (int m = 0; m < 2; m++) {
        if (!mtok[m]) continue;
        #pragma unroll
        for (int cc = 0; cc < 2; cc++) {
            int c = cg*2 + cc;
            #pragma unroll
            for (int n = 0; n < 2; n++) {
                int p = n*16 + (lane & 15);
                if (p >= 25) continue;
                #pragma unroll
                for (int q = 0; q < 4; q++) {
                    int j = mtv[m]*16 + (lane >> 4)*4 + q;
                    if (j < 100) {
                        size_t idx = eb + ((size_t)j*30 + c)*25 + p;
                        EPp[idx] = C0[m][cc][n][q];
                        EMp[idx] = C1[m][cc][n][q];
                    }
                }
            }
        }
    }
}

// ================= k_prep: build padded w2p from INPUT w2 + init flags =================
__global__ void k_prep(const float* __restrict__ w2, float* __restrict__ w2p,
                       int* __restrict__ qzf, int* __restrict__ pzf,
                       int* __restrict__ szf, int* __restrict__ eact) {
    int e = blockIdx.x*blockDim.x + threadIdx.x;
    if (e < 75000) {
        int j = e / 750, r = e % 750, c = r / 25, p = r % 25;
        w2p[((size_t)j*30 + c)*28 + p] = w2[e];
    }
    if (e < 512) qzf[e] = 1;
    if (e < 960) pzf[e] = 1;
    if (e < 416) szf[e] = 1;
    if (e < 480) eact[e] = 0;
}

// ================= k_fc1b: batched fc1, grid (500 n, 4 t-quarters) =================
__global__ __launch_bounds__(256) void k_fc1b(
        const float* __restrict__ g_all, const float* __restrict__ fcw,
        const float* __restrict__ fcb, float* __restrict__ h_all) {
    __shared__ float red[8][4];
    int n = blockIdx.x, by = blockIdx.y, tid = threadIdx.x;
    const float4* w4 = (const float4*)(fcw + (size_t)n*3200);
    float4 wreg[4];
    #pragma unroll
    for (int i = 0; i < 4; i++) {
        int k = tid + 256*i;
        if (k < 800) wreg[i] = w4[k];
    }
    float accs[8];
    #pragma unroll
    for (int tt = 0; tt < 8; tt++) accs[tt] = 0.f;
    #pragma unroll 1
    for (int tt = 0; tt < 8; tt++) {
        int t = by*8 + tt;
        const float4* g4 = (const float4*)(g_all + (size_t)t*3200);
        float a = 0.f;
        #pragma unroll
        for (int i = 0; i < 4; i++) {
            int k = tid + 256*i;
            if (k < 800) {
                float4 gv = g4[k];
                a = fmaf(gv.x, wreg[i].x, a);
                a = fmaf(gv.y, wreg[i].y, a);
                a = fmaf(gv.z, wreg[i].z, a);
                a = fmaf(gv.w, wreg[i].w, a);
            }
        }
        accs[tt] = a;
    }
    int lane = tid & 63, wid = tid >> 6;
    #pragma unroll
    for (int tt = 0; tt < 8; tt++) {
        float v = accs[tt];
        #pragma unroll
        for (int s = 32; s >= 1; s >>= 1) v += __shfl_down(v, s, 64);
        if (lane == 0) red[tt][wid] = v;
    }
    __syncthreads();
    if (tid < 8)
        h_all[(size_t)(by*8 + tid)*500 + n] =
            red[tid][0] + red[tid][1] + red[tid][2] + red[tid][3] + fcb[n];
}

// ================= k_head_all: LIF2 + LI readout =================
__global__ __launch_bounds__(640) void k_head_all(
        const float* __restrict__ h_all, const float* __restrict__ outw,
        float* __restrict__ out) {
    __shared__ float spk[500];
    __shared__ float vout[10];
    int tid = threadIdx.x;
    int wid = tid >> 6, lane = tid & 63;
    float v2r = 0.f, i2r = 0.f;
    float vor = 0.f, ior = 0.f;
    #pragma unroll 1
    for (int t = 0; t < 32; t++) {
        if (tid < 500) {
            float cur = i2r;
            float vd = v2r + DTMEM*(cur - v2r);
            float z = (vd > 1.0f) ? 1.0f : 0.0f;
            v2r = (1.0f - z)*vd;
            i2r = (cur - DTSYN*cur) + h_all[t*500 + tid];
            spk[tid] = z;
        }
        __syncthreads();
        float acc = 0.f;
        for (int n = lane; n < 500; n += 64)
            acc = fmaf(spk[n], outw[wid*500 + n], acc);
        #pragma unroll
        for (int s = 32; s >= 1; s >>= 1) acc += __shfl_down(acc, s, 64);
        if (lane == 0) {
            float ij = ior + acc;
            float vn = vor + DTMEM*(ij - vor);
            ior = ij - DTSYN*ij;
            vor = vn;
            vout[wid] = vn;
        }
        __syncthreads();
        if (tid < 320) out[(size_t)t*320 + tid] = vout[tid % 10];
        __syncthreads();
    }
}

// ---------------- launcher ----------------
extern "C" void kernel_launch(void* const* d_in, const int* in_sizes, int n_in,
                              void* d_out, int out_size, void* d_ws, size_t ws_size,
                              hipStream_t stream) {
    const float* x    = (const float*)d_in[0];
    const float* b1   = (const float*)d_in[1];
    const float* b2   = (const float*)d_in[2];
    const float* w1   = (const float*)d_in[3];
    const float* w2   = (const float*)d_in[4];
    const float* fcw  = (const float*)d_in[5];
    const float* fcb  = (const float*)d_in[6];
    const float* outw = (const float*)d_in[7];
    float* ws  = (float*)d_ws;
    float* out = (float*)d_out;

    DK dk;
    {
        float g1[25], g2[25], s1 = 0.f, s2 = 0.f;
        for (int i = 0; i < 5; i++)
            for (int j = 0; j < 5; j++) {
                float ai = (float)(i - 2), aj = (float)(j - 2);
                float r2 = ai*ai + aj*aj;
                g1[i*5+j] = expf(-r2/2.0f);
                g2[i*5+j] = expf(-r2/8.0f);
                s1 += g1[i*5+j]; s2 += g2[i*5+j];
            }
        for (int k = 0; k < 25; k++) dk.v[k] = g1[k]/s1 - g2[k]/s2;
    }

    int* qzf  = (int*)(ws + OQZF);
    int* pzf  = (int*)(ws + OPZF);
    int* szf  = (int*)(ws + OSZF);
    int* eact = (int*)(ws + OEAF);

    hipMemcpyAsync(ws + OW1, w1, 1500*sizeof(float), hipMemcpyDeviceToDevice, stream);
    hipMemsetAsync(ws + OV0, 0, (OZEND - OV0)*sizeof(float), stream);
    hipMemsetAsync(ws + OPHI, 0, (OTOT2 - OPHI)*sizeof(float), stream);  // bf16 planes must be zero (skip-write relies on it)
    k_prep<<<294, 256, 0, stream>>>(w2, ws + OW2P, qzf, pzf, szf, eact);

    for (int t = 0; t < T; t++) {
        const float* tp1r = ws + ((t & 1) ? OTP1B : OTP1A);
        float*       tp1w = ws + ((t & 1) ? OTP1A : OTP1B);
        k_front<<<dim3(8, 64, 2), 448, 0, stream>>>(
            x, b1, b2, ws+OW1, tp1r, tp1w, ws+OV0, ws+OI0, ws+OTQ1,
            ws+OZ3, ws+OTP2, ws+OP1, (int*)(ws+OCNZ), ws+OW2P,
            (unsigned short*)(ws+OPHI), (unsigned short*)(ws+OPLO),
            (unsigned short*)(ws+OPZ3),
            ws+OEPP, ws+OEMP, qzf, pzf, eact, dk, t);
        k_conv2lif<<<dim3(13, 32), 192, 0, stream>>>(
            ws+OW2P, ws+OZ3, (int*)(ws+OCNZ),
            ws+OV1S, ws+OI1S, ws+OTQ2S,
            (unsigned short*)(ws+OQZ4), (unsigned short*)(ws+OQHI),
            (unsigned short*)(ws+OQLO),
            ws+OG + (size_t)t*3200, szf, pzf);
        k_corr_mfma<<<dim3(32, 15, 2), 256, 0, stream>>>(
            (const unsigned short*)(ws+OPHI), (const unsigned short*)(ws+OPLO),
            (const unsigned short*)(ws+OPZ3),
            (const unsigned short*)(ws+OQZ4), (const unsigned short*)(ws+OQHI),
            (const unsigned short*)(ws+OQLO),
            ws+OG + (size_t)t*3200, (const int*)(ws+OCNZ),
            ws+OEPP, ws+OEMP, ws+OW1, ws+OP1, eact);
    }
    k_fc1b<<<dim3(500, 4), 256, 0, stream>>>(ws+OG, fcw, fcb, ws+OHH);
    k_head_all<<<1, 640, 0, stream>>>(ws+OHH, outw, out);
}